// Round 1
// baseline (9808.954 us; speedup 1.0000x reference)
//
#include <hip/hip_runtime.h>
#include <hip/hip_bf16.h>
#include <cstdint>

#define BATCH 64
#define SEQ   1024
#define ISZ   512
#define HSZ   512

// ---------------------------------------------------------------------------
// Phase 1: xw[m][n] = sum_k x[m][k] * Wih[k][n] + bih[n] + bhh[n]
// M = B*S = 65536, N = 512, K = 512.  Classic 64x64 tile, 256 threads, 4x4
// micro-tile per thread, fp32 VALU (no fp32 MFMA on CDNA4).
// Writes xw directly into the output buffer's [B,S,H] region; the recurrence
// kernel overwrites it in place with h_t.
// ---------------------------------------------------------------------------
__global__ __launch_bounds__(256)
void xw_gemm(const float* __restrict__ x, const float* __restrict__ Wih,
             const float* __restrict__ bih, const float* __restrict__ bhh,
             float* __restrict__ xw)
{
    __shared__ float As[16][64];   // As[k][m]  (A transposed on store)
    __shared__ float Bs[16][64];   // Bs[k][n]

    const int tid = threadIdx.x;
    const int tx  = tid & 15;      // n direction
    const int ty  = tid >> 4;      // m direction
    const int bm  = blockIdx.x;    // 0..1023
    const int bn  = blockIdx.y;    // 0..7

    const float* xblk = x   + (size_t)bm * 64 * ISZ;
    const float* wblk = Wih + bn * 64;

    // global loaders
    const int ar = tid >> 2;          // 0..63   (M row in tile)
    const int ac = (tid & 3) << 2;    // 0,4,8,12 (k offset)
    const int br = tid >> 4;          // 0..15   (k row)
    const int bc = (tid & 15) << 2;   // 0..60   (n col)

    float acc[4][4] = {};

    for (int kk = 0; kk < ISZ; kk += 16) {
        float4 a = *(const float4*)(xblk + (size_t)ar * ISZ + kk + ac);
        float4 b = *(const float4*)(wblk + (size_t)(kk + br) * HSZ + bc);
        __syncthreads();
        As[ac + 0][ar] = a.x;
        As[ac + 1][ar] = a.y;
        As[ac + 2][ar] = a.z;
        As[ac + 3][ar] = a.w;
        *(float4*)(&Bs[br][bc]) = b;
        __syncthreads();
        #pragma unroll
        for (int k = 0; k < 16; ++k) {
            float4 av = *(const float4*)(&As[k][ty * 4]);
            float4 bv = *(const float4*)(&Bs[k][tx * 4]);
            acc[0][0] = fmaf(av.x, bv.x, acc[0][0]);
            acc[0][1] = fmaf(av.x, bv.y, acc[0][1]);
            acc[0][2] = fmaf(av.x, bv.z, acc[0][2]);
            acc[0][3] = fmaf(av.x, bv.w, acc[0][3]);
            acc[1][0] = fmaf(av.y, bv.x, acc[1][0]);
            acc[1][1] = fmaf(av.y, bv.y, acc[1][1]);
            acc[1][2] = fmaf(av.y, bv.z, acc[1][2]);
            acc[1][3] = fmaf(av.y, bv.w, acc[1][3]);
            acc[2][0] = fmaf(av.z, bv.x, acc[2][0]);
            acc[2][1] = fmaf(av.z, bv.y, acc[2][1]);
            acc[2][2] = fmaf(av.z, bv.z, acc[2][2]);
            acc[2][3] = fmaf(av.z, bv.w, acc[2][3]);
            acc[3][0] = fmaf(av.w, bv.x, acc[3][0]);
            acc[3][1] = fmaf(av.w, bv.y, acc[3][1]);
            acc[3][2] = fmaf(av.w, bv.z, acc[3][2]);
            acc[3][3] = fmaf(av.w, bv.w, acc[3][3]);
        }
    }

    const int n0 = bn * 64 + tx * 4;
    float bias[4];
    #pragma unroll
    for (int j = 0; j < 4; ++j) bias[j] = bih[n0 + j] + bhh[n0 + j];

    #pragma unroll
    for (int i = 0; i < 4; ++i) {
        size_t m = (size_t)bm * 64 + ty * 4 + i;
        float4 v;
        v.x = acc[i][0] + bias[0];
        v.y = acc[i][1] + bias[1];
        v.z = acc[i][2] + bias[2];
        v.w = acc[i][3] + bias[3];
        *(float4*)(xw + m * HSZ + n0) = v;
    }
}

// ---------------------------------------------------------------------------
// Phase 2: the sequential recurrence.  One block per batch element (64 blocks,
// sync-free).  512 threads: thread = (kq, j4) with kq = k-quarter (0..3),
// j4 = 4-column group (0..127).  Each thread computes a partial over 128 k's
// for 4 consecutive output columns, then a cross-kq LDS reduction + tanh.
//   - h   : broadcast from LDS as float4 (32 ds_read_b128 / thread / step)
//   - W_hh: float4 loads, coalesced across lanes, L2-resident (1 MB / XCD)
// xw is read from the output buffer and h_t written back in place.
// ---------------------------------------------------------------------------
__global__ __launch_bounds__(512)
void rnn_rec(const float* __restrict__ Whh,
             float* __restrict__ out, float* __restrict__ hn)
{
    const int b   = blockIdx.x;
    const int tid = threadIdx.x;
    const int kq  = tid >> 7;           // 0..3
    const int j4  = (tid & 127) << 2;   // 0,4,...,508

    __shared__ float hs[HSZ];
    __shared__ float partial[4][HSZ + 4];   // +4 pad: conflict-free column reads

    hs[tid & (HSZ - 1)] = 0.0f;
    __syncthreads();

    float* row = out + (size_t)b * SEQ * HSZ;
    const float* wbase = Whh + (size_t)kq * 128 * HSZ + j4;

    for (int t = 0; t < SEQ; ++t, row += HSZ) {
        float4 acc = {0.f, 0.f, 0.f, 0.f};
        const float*  wp = wbase;
        const float4* hp = (const float4*)(hs + kq * 128);
        #pragma unroll 8
        for (int kkk = 0; kkk < 32; ++kkk, wp += 4 * HSZ) {
            float4 h4 = hp[kkk];
            float4 w0 = *(const float4*)(wp);
            float4 w1 = *(const float4*)(wp + HSZ);
            float4 w2 = *(const float4*)(wp + 2 * HSZ);
            float4 w3 = *(const float4*)(wp + 3 * HSZ);
            acc.x = fmaf(h4.x, w0.x, acc.x);
            acc.y = fmaf(h4.x, w0.y, acc.y);
            acc.z = fmaf(h4.x, w0.z, acc.z);
            acc.w = fmaf(h4.x, w0.w, acc.w);
            acc.x = fmaf(h4.y, w1.x, acc.x);
            acc.y = fmaf(h4.y, w1.y, acc.y);
            acc.z = fmaf(h4.y, w1.z, acc.z);
            acc.w = fmaf(h4.y, w1.w, acc.w);
            acc.x = fmaf(h4.z, w2.x, acc.x);
            acc.y = fmaf(h4.z, w2.y, acc.y);
            acc.z = fmaf(h4.z, w2.z, acc.z);
            acc.w = fmaf(h4.z, w2.w, acc.w);
            acc.x = fmaf(h4.w, w3.x, acc.x);
            acc.y = fmaf(h4.w, w3.y, acc.y);
            acc.z = fmaf(h4.w, w3.z, acc.z);
            acc.w = fmaf(h4.w, w3.w, acc.w);
        }
        *(float4*)(&partial[kq][j4]) = acc;
        __syncthreads();

        // one thread per output column
        const int j = tid;
        float s = partial[0][j] + partial[1][j] + partial[2][j] + partial[3][j]
                + row[j];
        float h = tanhf(s);
        row[j] = h;   // overwrite xw with h_t  (output)
        hs[j]  = h;   // safe: all reads of hs for this step happened pre-barrier
        __syncthreads();
    }

    hn[(size_t)b * HSZ + tid] = hs[tid];
}

extern "C" void kernel_launch(void* const* d_in, const int* in_sizes, int n_in,
                              void* d_out, int out_size, void* d_ws, size_t ws_size,
                              hipStream_t stream) {
    const float* x    = (const float*)d_in[0];
    const float* Wih  = (const float*)d_in[1];
    const float* bih  = (const float*)d_in[2];
    const float* Whh  = (const float*)d_in[3];
    const float* bhh  = (const float*)d_in[4];

    float* out = (float*)d_out;                       // [B,S,H]
    float* hn  = out + (size_t)BATCH * SEQ * HSZ;     // [1,B,H]

    dim3 g1((BATCH * SEQ) / 64, HSZ / 64);            // (1024, 8)
    xw_gemm<<<g1, 256, 0, stream>>>(x, Wih, bih, bhh, out);
    rnn_rec<<<BATCH, 512, 0, stream>>>(Whh, out, hn);
}

// Round 8
// 2168.943 us; speedup vs baseline: 4.5225x; 4.5225x over previous
//
#include <hip/hip_runtime.h>
#include <hip/hip_bf16.h>
#include <cstdint>

#define BATCH 64
#define SEQ   1024
#define ISZ   512
#define HSZ   512

// ---------------------------------------------------------------------------
// Phase 1: xw[m][n] = sum_k x[m][k] * Wih[k][n] + bih[n] + bhh[n]
// (unchanged — ~420us; optimize once the recurrence is correct+fast)
// ---------------------------------------------------------------------------
__global__ __launch_bounds__(256)
void xw_gemm(const float* __restrict__ x, const float* __restrict__ Wih,
             const float* __restrict__ bih, const float* __restrict__ bhh,
             float* __restrict__ xw)
{
    __shared__ float As[16][64];   // As[k][m]
    __shared__ float Bs[16][64];   // Bs[k][n]

    const int tid = threadIdx.x;
    const int tx  = tid & 15;
    const int ty  = tid >> 4;
    const int bm  = blockIdx.x;
    const int bn  = blockIdx.y;

    const float* xblk = x   + (size_t)bm * 64 * ISZ;
    const float* wblk = Wih + bn * 64;

    const int ar = tid >> 2;
    const int ac = (tid & 3) << 2;
    const int br = tid >> 4;
    const int bc = (tid & 15) << 2;

    float acc[4][4] = {};

    for (int kk = 0; kk < ISZ; kk += 16) {
        float4 a = *(const float4*)(xblk + (size_t)ar * ISZ + kk + ac);
        float4 b = *(const float4*)(wblk + (size_t)(kk + br) * HSZ + bc);
        __syncthreads();
        As[ac + 0][ar] = a.x;
        As[ac + 1][ar] = a.y;
        As[ac + 2][ar] = a.z;
        As[ac + 3][ar] = a.w;
        *(float4*)(&Bs[br][bc]) = b;
        __syncthreads();
        #pragma unroll
        for (int k = 0; k < 16; ++k) {
            float4 av = *(const float4*)(&As[k][ty * 4]);
            float4 bv = *(const float4*)(&Bs[k][tx * 4]);
            acc[0][0] = fmaf(av.x, bv.x, acc[0][0]);
            acc[0][1] = fmaf(av.x, bv.y, acc[0][1]);
            acc[0][2] = fmaf(av.x, bv.z, acc[0][2]);
            acc[0][3] = fmaf(av.x, bv.w, acc[0][3]);
            acc[1][0] = fmaf(av.y, bv.x, acc[1][0]);
            acc[1][1] = fmaf(av.y, bv.y, acc[1][1]);
            acc[1][2] = fmaf(av.y, bv.z, acc[1][2]);
            acc[1][3] = fmaf(av.y, bv.w, acc[1][3]);
            acc[2][0] = fmaf(av.z, bv.x, acc[2][0]);
            acc[2][1] = fmaf(av.z, bv.y, acc[2][1]);
            acc[2][2] = fmaf(av.z, bv.z, acc[2][2]);
            acc[2][3] = fmaf(av.z, bv.w, acc[2][3]);
            acc[3][0] = fmaf(av.w, bv.x, acc[3][0]);
            acc[3][1] = fmaf(av.w, bv.y, acc[3][1]);
            acc[3][2] = fmaf(av.w, bv.z, acc[3][2]);
            acc[3][3] = fmaf(av.w, bv.w, acc[3][3]);
        }
    }

    const int n0 = bn * 64 + tx * 4;
    float bias[4];
    #pragma unroll
    for (int j = 0; j < 4; ++j) bias[j] = bih[n0 + j] + bhh[n0 + j];

    #pragma unroll
    for (int i = 0; i < 4; ++i) {
        size_t m = (size_t)bm * 64 + ty * 4 + i;
        float4 v;
        v.x = acc[i][0] + bias[0];
        v.y = acc[i][1] + bias[1];
        v.z = acc[i][2] + bias[2];
        v.w = acc[i][3] + bias[3];
        *(float4*)(xw + m * HSZ + n0) = v;
    }
}

// ---------------------------------------------------------------------------
// Phase 2: recurrence, W_hh register-resident, 4 blocks per batch.
//   grid = 256 blocks (1/CU, co-resident), 512 threads; block role q owns
//   output columns [128q,128q+128); W slice = 32 x float4 = 128 VGPR/thread.
//
//   Cross-block handoff (round-4 race fix):
//     - one 64-bit word per (parity, batch, column): tag(step+1)<<32 | h bits.
//       Data+flag are a single atomic location -> no fence reasoning needed.
//     - parity double-buffer buf[step&1]: a writer reaches step s+2 (the
//       first overwrite of parity buffer s&1) only after passing its own
//       step-(s+1) poll, which requires every peer to have posted h_{s+1},
//       which requires that peer to have CONSUMED h_s.  <=1 step skew, full
//       back-pressure.  Exact tag match (not >=) rejects stale AND future.
//     - poison 0xAA never matches tags 1..1023 -> no memset required.
// ---------------------------------------------------------------------------
__global__ __launch_bounds__(512, 2)
void rnn_rec4(const float* __restrict__ Whh,
              float* __restrict__ out, float* __restrict__ hn,
              uint64_t* __restrict__ xchg)      // [2][BATCH][HSZ]
{
    const int bid = blockIdx.x;
    const int q   = (bid >> 3) & 3;                  // role 0..3
    const int b   = (bid & 7) | ((bid >> 5) << 3);   // batch 0..63
    const int t   = threadIdx.x;
    const int kg  = t >> 5;            // 0..15  k-range [32kg, 32kg+32)
    const int jo4 = (t & 31) << 2;     // 0..124 local column group
    const int jbase = q * 128;
    const int jl  = t & 127;

    __shared__ float hs[HSZ];
    __shared__ float partial[16][132];

    // ---- preload W slice into registers (once) ----
    float4 Wr[32];
    {
        const float* wp = Whh + (size_t)(kg * 32) * HSZ + jbase + jo4;
        #pragma unroll
        for (int i = 0; i < 32; ++i)
            Wr[i] = *(const float4*)(wp + (size_t)i * HSZ);
    }

    hs[t] = 0.0f;
    __syncthreads();

    float* rowbase = out + (size_t)b * SEQ * HSZ + jbase;
    uint64_t* xb[2] = { xchg + (size_t)b * HSZ,
                        xchg + (size_t)(BATCH + b) * HSZ };

    float hlast = 0.0f;

    for (int step = 0; step < SEQ; ++step) {
        float* row = rowbase + (size_t)step * HSZ;
        float xwv = 0.0f;
        if (t < 128) xwv = row[jl];          // independent load, issues early

        // ---- partials: 8 ds_read_b128 + 128 FMA per thread ----
        float4 acc = {0.f, 0.f, 0.f, 0.f};
        #pragma unroll
        for (int i8 = 0; i8 < 8; ++i8) {
            float4 h4 = *(const float4*)(&hs[kg * 32 + i8 * 4]);
            #pragma unroll
            for (int ii = 0; ii < 4; ++ii) {
                const float hv = (&h4.x)[ii];
                const float4 w = Wr[i8 * 4 + ii];
                acc.x = fmaf(hv, w.x, acc.x);
                acc.y = fmaf(hv, w.y, acc.y);
                acc.z = fmaf(hv, w.z, acc.z);
                acc.w = fmaf(hv, w.w, acc.w);
            }
        }
        *(float4*)(&partial[kg][jo4]) = acc;
        __syncthreads();                                   // (A)

        const bool notlast = (step < SEQ - 1);
        uint64_t* buf = xb[step & 1];
        const uint32_t tag = (uint32_t)(step + 1);

        if (t < 128) {
            float s = xwv;
            #pragma unroll
            for (int p = 0; p < 16; ++p) s += partial[p][jl];
            const float h = tanhf(s);
            row[jl] = h;                 // output h_t (overwrites xw in place)
            hs[jbase + jl] = h;          // own slice for next step
            hlast = h;
            if (notlast) {
                const uint64_t word =
                    ((uint64_t)tag << 32) | (uint64_t)__float_as_uint(h);
                __hip_atomic_store(&buf[jbase + jl], word,
                                   __ATOMIC_RELAXED, __HIP_MEMORY_SCOPE_AGENT);
            }
        }

        if (notlast) {
            if (t >= 128) {
                const int peer = (q + (t >> 7)) & 3;       // 3 groups x 128
                uint64_t* p = &buf[peer * 128 + jl];
                uint64_t w;
                int guard = 0;
                do {
                    w = __hip_atomic_load(p, __ATOMIC_RELAXED,
                                          __HIP_MEMORY_SCOPE_AGENT);
                } while ((uint32_t)(w >> 32) != tag && ++guard < (1 << 22));
                hs[peer * 128 + jl] = __uint_as_float((uint32_t)w);
            }
            __syncthreads();                               // (C) hs complete
        }
    }

    if (t < 128) hn[(size_t)b * HSZ + jbase + jl] = hlast;
}

extern "C" void kernel_launch(void* const* d_in, const int* in_sizes, int n_in,
                              void* d_out, int out_size, void* d_ws, size_t ws_size,
                              hipStream_t stream) {
    const float* x    = (const float*)d_in[0];
    const float* Wih  = (const float*)d_in[1];
    const float* bih  = (const float*)d_in[2];
    const float* Whh  = (const float*)d_in[3];
    const float* bhh  = (const float*)d_in[4];

    float* out = (float*)d_out;                       // [B,S,H]
    float* hn  = out + (size_t)BATCH * SEQ * HSZ;     // [1,B,H]

    // workspace: tagged exchange words [2][BATCH][HSZ] = 512 KB.
    // No init needed: 0xAA poison never matches a valid tag (1..1023).
    uint64_t* xchg = (uint64_t*)d_ws;

    dim3 g1((BATCH * SEQ) / 64, HSZ / 64);            // (1024, 8)
    xw_gemm<<<g1, 256, 0, stream>>>(x, Wih, bih, bhh, out);
    rnn_rec4<<<256, 512, 0, stream>>>(Whh, out, hn, xchg);
}